// Round 8
// baseline (94.423 us; speedup 1.0000x reference)
//
#include <hip/hip_runtime.h>
#include <cstdint>
#include <cstddef>

// PNNLayer collapse:  out[n,:] = dists[n,:] @ P + embeds[n,:] @ W2 + b
//   P = (1/32) * (embeds[anchorset_id] @ W1)   [32 x 64] constant
//   => one GEMM: X [100000 x 96] @ Wcat [96 x 64], Wcat = [P ; W2]
// dtypes (verified R3): all f32 in/out, ids int32. MFMA via split-bf16 (3-term).
//
// R8: SINGLE kernel. Each block rebuilds the 24.6 KB B-fragment table in its
// own LDS: waves 0-1 compute P via a 24-MFMA mini-GEMM (anchors A-staged in
// As, W1 frags straight from global); all waves pack W2 (coalesced). Removes
// the prep dispatch + drain (~4-5 us of the 19 us kernel-side time). Main
// persistent loop is unchanged from validated R7.

#define N_NODES 100000
#define DIM     64
#define NTILES  1563     // ceil(100000 / 64)
#define GRID    768      // exactly 3 blocks/CU resident; ~2 tiles/block
#define AS_K    104      // A-tile row stride in ushorts (16B-aligned, spread banks)

typedef short bf16x8 __attribute__((ext_vector_type(8)));   // 8 bf16 = 4 VGPRs
typedef float f32x4  __attribute__((ext_vector_type(4)));   // MFMA acc

__device__ __forceinline__ unsigned short f2bf(float f) {
    union { float f; unsigned u; } c; c.f = f;
    return (unsigned short)((c.u + 0x7fffu + ((c.u >> 16) & 1u)) >> 16);  // RNE
}
__device__ __forceinline__ float bf2f(unsigned short h) {
    union { unsigned u; float f; } c; c.u = ((unsigned)h) << 16; return c.f;
}
__device__ __forceinline__ unsigned long long pack4h(float a, float b, float c, float d) {
    unsigned short h0 = f2bf(a), h1 = f2bf(b), h2 = f2bf(c), h3 = f2bf(d);
    return (unsigned long long)h0 | ((unsigned long long)h1 << 16) |
           ((unsigned long long)h2 << 32) | ((unsigned long long)h3 << 48);
}
__device__ __forceinline__ unsigned long long pack4l(float a, float b, float c, float d) {
    unsigned short l0 = f2bf(a - bf2f(f2bf(a))), l1 = f2bf(b - bf2f(f2bf(b)));
    unsigned short l2 = f2bf(c - bf2f(f2bf(c))), l3 = f2bf(d - bf2f(f2bf(d)));
    return (unsigned long long)l0 | ((unsigned long long)l1 << 16) |
           ((unsigned long long)l2 << 32) | ((unsigned long long)l3 << 48);
}

#define LOAD_TILE(m0)                                                          \
    do {                                                                       \
        const float4* dg = (const float4*)(dists + (size_t)(m0) * 32);         \
        _Pragma("unroll")                                                      \
        for (int i = 0; i < 2; ++i) {                                          \
            const int f = i * 256 + tid;                                       \
            dv[i] = ((m0) + (f >> 3) < N_NODES) ? dg[f]                        \
                                                : make_float4(0.f,0.f,0.f,0.f);\
        }                                                                      \
        const float4* eg = (const float4*)(embeds + (size_t)(m0) * 64);        \
        _Pragma("unroll")                                                      \
        for (int i = 0; i < 4; ++i) {                                          \
            const int f = i * 256 + tid;                                       \
            ev[i] = ((m0) + (f >> 4) < N_NODES) ? eg[f]                        \
                                                : make_float4(0.f,0.f,0.f,0.f);\
        }                                                                      \
    } while (0)

// sB element layout (ushort): idx = (((ks*4+nt)*2+pl)*64 + lane)*8 + j,
//   element = Wcat[k = ks*32 + (lane>>4)*8 + j][n = nt*16 + (lane&15)]
__global__ __launch_bounds__(256, 3) void pnn_fused(
    const float* __restrict__ embeds,
    const float* __restrict__ dists,
    const float* __restrict__ W,        // [128,64]: rows 0..63 = W1, 64..127 = W2
    const float* __restrict__ bias,
    const int*   __restrict__ aid,      // [32]
    float* __restrict__ out)            // [N,64] f32
{
    __shared__ __align__(16) unsigned short sB[12288];          // 24 KB B-frags
    __shared__ __align__(16) unsigned short As[2][4][16][AS_K]; // 26 KB A-tile
    // total 50 KB static -> 3 blocks/CU (LDS-capped)

    const int tid  = threadIdx.x;
    const int wave = tid >> 6;
    const int lane = tid & 63;
    const int quad = lane >> 4;
    const int col  = lane & 15;

    // ---- first tile's globals: issue immediately, land during preamble ----
    int tile = blockIdx.x;
    float4 dv[2], ev[4];
    LOAD_TILE(tile * 64);

    // ---- W2 pack: 16 coalesced f32 loads/thread -> hi+lo b16 LDS writes ----
    #pragma unroll
    for (int i = 0; i < 16; ++i) {
        const int e  = i * 256 + tid;       // 0..4095 over block
        const int n  = e & 63;              // coalesced across tid
        const int kk = e >> 6;              // W2 row 0..63
        const float v = W[(kk + 64) * DIM + n];
        const int ks  = 1 + (kk >> 5);      // 1..2
        const int rem = kk & 31;
        const int jj  = rem & 7;
        const int ln2 = (rem >> 3) * 16 + (n & 15);
        const int nt  = n >> 4;
        const unsigned short hi = f2bf(v);
        sB[(((ks * 4 + nt) * 2 + 0) * 64 + ln2) * 8 + jj] = hi;
        sB[(((ks * 4 + nt) * 2 + 1) * 64 + ln2) * 8 + jj] = f2bf(v - bf2f(hi));
    }

    // ---- anchor rows -> As in A-frag layout (rows 0..31, k 0..63) ----
    #pragma unroll
    for (int i = 0; i < 2; ++i) {
        const int fa  = i * 256 + tid;      // 0..511 float4-slots
        const int row = fa >> 4;            // anchor 0..31
        const int c4  = fa & 15;            // float4 within row
        const float4 v = ((const float4*)(embeds + (size_t)aid[row] * DIM))[c4];
        *(unsigned long long*)&As[0][row >> 4][row & 15][c4 * 4] = pack4h(v.x, v.y, v.z, v.w);
        *(unsigned long long*)&As[1][row >> 4][row & 15][c4 * 4] = pack4l(v.x, v.y, v.z, v.w);
    }
    __syncthreads();

    // ---- waves 0,1: P = anchors @ W1 via MFMA, scaled, packed into sB(ks=0) ----
    if (wave < 2) {
        f32x4 accP[4];
        #pragma unroll
        for (int nt = 0; nt < 4; ++nt) accP[nt] = (f32x4){0.f, 0.f, 0.f, 0.f};
        #pragma unroll
        for (int ks2 = 0; ks2 < 2; ++ks2) {
            const bf16x8 Ahi = *(const bf16x8*)&As[0][wave][col][ks2 * 32 + quad * 8];
            const bf16x8 Alo = *(const bf16x8*)&As[1][wave][col][ks2 * 32 + quad * 8];
            #pragma unroll
            for (int nt = 0; nt < 4; ++nt) {
                float w8[8];
                #pragma unroll
                for (int j = 0; j < 8; ++j)     // W1 element [k][n], frag order
                    w8[j] = W[(ks2 * 32 + quad * 8 + j) * DIM + nt * 16 + col];
                bf16x8 Bh, Bo;
                #pragma unroll
                for (int j = 0; j < 8; ++j) {
                    const unsigned short h = f2bf(w8[j]);
                    Bh[j] = (short)h;
                    Bo[j] = (short)f2bf(w8[j] - bf2f(h));
                }
                accP[nt] = __builtin_amdgcn_mfma_f32_16x16x32_bf16(Ahi, Bh, accP[nt], 0, 0, 0);
                accP[nt] = __builtin_amdgcn_mfma_f32_16x16x32_bf16(Alo, Bh, accP[nt], 0, 0, 0);
                accP[nt] = __builtin_amdgcn_mfma_f32_16x16x32_bf16(Ahi, Bo, accP[nt], 0, 0, 0);
            }
        }
        // D[m = quad*4+r][n = col] -> P row a = wave*16+quad*4+r ; pack hi/lo
        #pragma unroll
        for (int r = 0; r < 4; ++r) {
            const int a  = wave * 16 + quad * 4 + r;
            const int jj = a & 7;
            const int q2 = a >> 3;
            #pragma unroll
            for (int nt = 0; nt < 4; ++nt) {
                const float s = accP[nt][r] * (1.0f / 32.0f);
                const int ln2 = q2 * 16 + col;
                const unsigned short hi = f2bf(s);
                sB[((nt * 2 + 0) * 64 + ln2) * 8 + jj] = hi;              // ks=0, pl=0
                sB[((nt * 2 + 1) * 64 + ln2) * 8 + jj] = f2bf(s - bf2f(hi)); // pl=1
            }
        }
    }

    float bias_n[4];
    #pragma unroll
    for (int nt = 0; nt < 4; ++nt) bias_n[nt] = bias[nt * 16 + col];

    __syncthreads();   // sB complete; As free for tile staging

    // ================= main persistent loop (validated R7) =================
    for (; tile < NTILES; tile += GRID) {
        const int n0 = tile * 64;

        #pragma unroll
        for (int i = 0; i < 2; ++i) {           // dists -> k = 0..31
            const int f  = i * 256 + tid;
            const int nd = f >> 3, k0 = (f & 7) * 4;
            const float4 v = dv[i];
            *(unsigned long long*)&As[0][nd >> 4][nd & 15][k0] = pack4h(v.x, v.y, v.z, v.w);
            *(unsigned long long*)&As[1][nd >> 4][nd & 15][k0] = pack4l(v.x, v.y, v.z, v.w);
        }
        #pragma unroll
        for (int i = 0; i < 4; ++i) {           // embeds -> k = 32..95
            const int f  = i * 256 + tid;
            const int nd = f >> 4, k0 = 32 + (f & 15) * 4;
            const float4 v = ev[i];
            *(unsigned long long*)&As[0][nd >> 4][nd & 15][k0] = pack4h(v.x, v.y, v.z, v.w);
            *(unsigned long long*)&As[1][nd >> 4][nd & 15][k0] = pack4l(v.x, v.y, v.z, v.w);
        }
        __syncthreads();

        // prefetch next tile's globals (in flight through MFMA + store)
        const int t2 = tile + GRID;
        if (t2 < NTILES) {                      // block-uniform branch
            LOAD_TILE(t2 * 64);
        }

        f32x4 acc[4];
        #pragma unroll
        for (int nt = 0; nt < 4; ++nt) {
            const float bb = bias_n[nt];
            acc[nt][0] = bb; acc[nt][1] = bb; acc[nt][2] = bb; acc[nt][3] = bb;
        }
        const bf16x8* Bl = (const bf16x8*)sB;
        #pragma unroll
        for (int ks = 0; ks < 3; ++ks) {
            const bf16x8 Ahi = *(const bf16x8*)&As[0][wave][col][ks * 32 + quad * 8];
            const bf16x8 Alo = *(const bf16x8*)&As[1][wave][col][ks * 32 + quad * 8];
            #pragma unroll
            for (int nt = 0; nt < 4; ++nt) {
                const bf16x8 Bh = Bl[((ks * 4 + nt) * 2 + 0) * 64 + lane];
                const bf16x8 Bo = Bl[((ks * 4 + nt) * 2 + 1) * 64 + lane];
                acc[nt] = __builtin_amdgcn_mfma_f32_16x16x32_bf16(Ahi, Bh, acc[nt], 0, 0, 0);
                acc[nt] = __builtin_amdgcn_mfma_f32_16x16x32_bf16(Ahi, Bo, acc[nt], 0, 0, 0);
                acc[nt] = __builtin_amdgcn_mfma_f32_16x16x32_bf16(Alo, Bh, acc[nt], 0, 0, 0);
            }
        }

        #pragma unroll
        for (int r = 0; r < 4; ++r) {           // D row = node, col = dim
            const int node = n0 + wave * 16 + quad * 4 + r;
            if (node < N_NODES) {
                float* po = out + (size_t)node * DIM + col;
                #pragma unroll
                for (int nt = 0; nt < 4; ++nt) po[nt * 16] = acc[nt][r];
            }
        }
        __syncthreads();   // As reusable for next iteration's staging
    }
}

extern "C" void kernel_launch(void* const* d_in, const int* in_sizes, int n_in,
                              void* d_out, int out_size, void* d_ws, size_t ws_size,
                              hipStream_t stream) {
    const float* embeds = (const float*)d_in[0];   // [100000,64] f32
    const float* dists  = (const float*)d_in[1];   // [100000,32] f32
    const float* W      = (const float*)d_in[2];   // [128,64] f32
    const float* bias   = (const float*)d_in[3];   // [64] f32
    const int*   aid    = (const int*)d_in[4];     // [32] int32
    float* out = (float*)d_out;                    // [100000,64] f32
    (void)d_ws; (void)ws_size;                     // workspace unused

    pnn_fused<<<GRID, 256, 0, stream>>>(embeds, dists, W, bias, aid, out);
}